// Round 10
// baseline (556.826 us; speedup 1.0000x reference)
//
#include <hip/hip_runtime.h>
#include <hip/hip_bf16.h>

#define BATCH 64
#define CIN   16
#define H     256
#define W     256
#define HW    (H*W)
#define COUT  64
#define HO    254
#define WO    254

#define TS      16           // output tile edge
#define TIN     18           // staged input tile edge
#define CELL    24           // ushorts per (y,x) cell: 16 ci + 8 pad (48B)
#define NTY     8            // y-tiles per block (half strip)
#define NITEMS  (4*TIN*TIN)  // 1296 staging items per tile
#define THREADS 512          // 8 waves
#define IPT     3            // 2 full + 1 partial (272)

typedef short  bf16x8 __attribute__((ext_vector_type(8)));
typedef float  f32x16 __attribute__((ext_vector_type(16)));

static __device__ __forceinline__ unsigned short bfbits(float f) {
    __hip_bfloat16 h = __float2bfloat16(f);
    return *(unsigned short*)&h;
}

static __device__ __forceinline__ bf16x8 ld_frag(const ushort* p) {
    union { uint4 u; bf16x8 b; } cv;
    cv.u = *(const uint4*)p;
    return cv.b;
}

static __device__ __forceinline__ float fast_tanh(float x) {
    x = fminf(fmaxf(x, -15.f), 15.f);
    float e = __expf(2.f * x);
    return (e - 1.f) * __builtin_amdgcn_rcpf(e + 1.f);
}

// ---- repack: w -> wpk[tap][cout][ci] bf16 (taps 0-8); tap 9 = bias column ----
__global__ void repack_w(const float* __restrict__ w, const float* __restrict__ bias,
                         ushort* __restrict__ wpk) {
    int i = blockIdx.x * 256 + threadIdx.x;
    if (i < 9 * COUT * CIN) {
        int ci   = i & 15;
        int cout = (i >> 4) & 63;
        int tap  = i >> 10;
        wpk[i] = bfbits(w[(cout * CIN + ci) * 9 + tap]);
    } else if (i < 10 * COUT * CIN) {
        int j    = i - 9 * COUT * CIN;
        int ci   = j & 15;
        int cout = j >> 4;
        wpk[i] = (ci == 0) ? bfbits(bias[cout]) : (ushort)0;
    }
}

// Occupancy round: 8 waves x 32px each (acc = 32 VGPR), weights streamed from
// L1, bias as 10th MFMA tap, waves_per_eu(6,8) caps VGPR ~84 -> 6 waves/SIMD.
// Round-9 counters: latency-bound (all pipes <30%, ~2 blocks/CU resident).
__global__ __launch_bounds__(THREADS) __attribute__((amdgpu_waves_per_eu(6, 8)))
void conv_min_tanh_strip8(const float* __restrict__ x,
                          const ushort* __restrict__ wpk,
                          float* __restrict__ out) {
    __shared__ __align__(16) ushort xsm[2][TIN * TIN * CELL];  // 2 x 15552 B

    // bijective XCD swizzle (2048 % 8 == 0)
    const int bid = blockIdx.x;                 // 0..2047
    const int L   = (bid & 7) * 256 + (bid >> 3);
    const int b   = L >> 5;
    const int rr  = L & 31;
    const int yb0 = (rr >> 4) * (NTY * TS);     // 0 or 128
    const int x0  = (rr & 15) * TS;

    const int tid  = threadIdx.x;
    const int lane = tid & 63;
    const int wv   = tid >> 6;    // 0..7
    const int l31  = lane & 31;
    const int hi   = lane >> 5;   // k half: ci 0-7 vs 8-15

    const float* xp0 = x + (size_t)b * (CIN * HW);
    const float* xp1 = xp0 + HW;
    const float* xp2 = xp0 + 2 * HW;
    const float* xp3 = xp0 + 3 * HW;

    // ones B-frag for the bias tap (k=0 lives in hi==0, elem 0)
    bf16x8 pone;
    #pragma unroll
    for (int j = 0; j < 8; ++j) pone[j] = 0;
    if (hi == 0) pone[0] = (short)0x3F80;

    // ---- staging address precompute (x-clamp REQUIRED: round-4 crash) ----
    int c0[IPT], dyv[IPT], lo[IPT];
    #pragma unroll
    for (int k = 0; k < IPT; ++k) {
        int it = tid + k * THREADS;
        int dx = it % TIN;
        int t2 = it / TIN;
        int dy = t2 % TIN;
        int cg = t2 / TIN;
        c0[k]  = cg * 4 * HW + min(x0 + dx, W - 1);
        dyv[k] = dy;
        lo[k]  = (dy * TIN + dx) * CELL + cg * 4;
    }

    // B-frag cell base: this wave's 32 px = rows {2wv, 2wv+1} x cols 0..15
    // row = wv*2 + (l31>>4), col = l31&15, k = ci = hi*8+j
    const int cb = ((wv * 2 + (l31 >> 4)) * TIN + (l31 & 15)) * CELL + hi * 8;

    float fx[IPT][4];

    auto stage_load = [&](int ybase) {
        #pragma unroll
        for (int k = 0; k < IPT; ++k) {
            if (k < IPT - 1 || tid < NITEMS - (IPT - 1) * THREADS) {
                int gy  = min(ybase + dyv[k], H - 1);
                int idx = c0[k] + (gy << 8);
                fx[k][0] = xp0[idx];
                fx[k][1] = xp1[idx];
                fx[k][2] = xp2[idx];
                fx[k][3] = xp3[idx];
            }
        }
    };
    auto stage_write = [&](int buf) {
        #pragma unroll
        for (int k = 0; k < IPT; ++k) {
            if (k < IPT - 1 || tid < NITEMS - (IPT - 1) * THREADS) {
                ushort4 v;
                v.x = bfbits(fx[k][0]);
                v.y = bfbits(fx[k][1]);
                v.z = bfbits(fx[k][2]);
                v.w = bfbits(fx[k][3]);
                *(ushort4*)&xsm[buf][lo[k]] = v;
            }
        }
    };

    // ---- prologue: stage tile 0 ----
    stage_load(yb0);
    stage_write(0);
    __syncthreads();

    #pragma unroll 1
    for (int t = 0; t < NTY; ++t) {
        const int cur = t & 1;

        // issue next tile's global loads before compute
        if (t + 1 < NTY) stage_load(yb0 + (t + 1) * TS);

        f32x16 acc[2];
        #pragma unroll
        for (int r = 0; r < 16; ++r) { acc[0][r] = 0.f; acc[1][r] = 0.f; }

        const ushort* xt = &xsm[cur][0];
        #pragma unroll
        for (int tap = 0; tap < 9; ++tap) {
            const int kh = tap / 3, kw = tap - 3 * kh;
            bf16x8 p  = ld_frag(xt + cb + (kh * TIN + kw) * CELL);
            bf16x8 w0 = ld_frag(wpk + tap * 1024 + l31 * 16 + hi * 8);          // couts 0-31 (L1)
            bf16x8 w1 = ld_frag(wpk + tap * 1024 + (32 + l31) * 16 + hi * 8);   // couts 32-63
            acc[0] = __builtin_amdgcn_mfma_f32_32x32x16_bf16(w0, p, acc[0], 0, 0, 0);
            acc[1] = __builtin_amdgcn_mfma_f32_32x32x16_bf16(w1, p, acc[1], 0, 0, 0);
        }
        // bias tap: D[cout][px] += bias[cout] * 1
        {
            bf16x8 w0 = ld_frag(wpk + 9 * 1024 + l31 * 16 + hi * 8);
            bf16x8 w1 = ld_frag(wpk + 9 * 1024 + (32 + l31) * 16 + hi * 8);
            acc[0] = __builtin_amdgcn_mfma_f32_32x32x16_bf16(w0, pone, acc[0], 0, 0, 0);
            acc[1] = __builtin_amdgcn_mfma_f32_32x32x16_bf16(w1, pone, acc[1], 0, 0, 0);
        }

        // ---- epilogue: min over 64 couts (in-reg tree + one cross-half shfl) ----
        float v[16];
        #pragma unroll
        for (int r = 0; r < 16; ++r)
            v[r] = fminf(acc[0][r], acc[1][r]);          // min over the 2 M-tiles
        #pragma unroll
        for (int s = 8; s >= 1; s >>= 1)
            #pragma unroll
            for (int r = 0; r < s; ++r)
                v[r] = fminf(v[r], v[r + s]);            // 32 couts in this half
        float val = fminf(v[0], __shfl_xor(v[0], 32, 64));  // + other 32 couts

        int oy = yb0 + t * TS + wv * 2 + (l31 >> 4);
        int ox = x0 + (l31 & 15);
        if (hi == 0 && oy < HO && ox < WO)
            out[((size_t)b * HO + oy) * WO + ox] = fast_tanh(fast_tanh(val));

        // write staged regs into the other buffer
        if (t + 1 < NTY) stage_write(cur ^ 1);
        __syncthreads();
    }
}

extern "C" void kernel_launch(void* const* d_in, const int* in_sizes, int n_in,
                              void* d_out, int out_size, void* d_ws, size_t ws_size,
                              hipStream_t stream) {
    const float* x    = (const float*)d_in[0];
    const float* w    = (const float*)d_in[1];
    const float* bias = (const float*)d_in[2];
    float* out        = (float*)d_out;
    ushort* wpk       = (ushort*)d_ws;   // 10*64*16 bf16 = 20480 B

    hipLaunchKernelGGL(repack_w, dim3(40), dim3(256), 0, stream, w, bias, wpk);
    hipLaunchKernelGGL(conv_min_tanh_strip8, dim3(2048), dim3(THREADS), 0, stream,
                       x, wpk, out);
}

// Round 11
// 135.084 us; speedup vs baseline: 4.1221x; 4.1221x over previous
//
#include <hip/hip_runtime.h>
#include <hip/hip_bf16.h>

#define BATCH 64
#define CIN   16
#define H     256
#define W     256
#define HW    (H*W)
#define COUT  64
#define HO    254
#define WO    254

#define TS      16            // output tile edge
#define TIN     18            // staged input tile edge
#define CELL    24            // ushorts per (y,x) cell: 16 ci + 8 pad (48B, 16B-aligned)
#define NTY     8             // y-tiles per block (half strip)
#define THREADS 512           // 8 waves
#define NQUAD   360           // staging quad-items per tile: 4 cg x 18 dy x 5 q

typedef short  bf16x8 __attribute__((ext_vector_type(8)));
typedef float  f32x16 __attribute__((ext_vector_type(16)));

static __device__ __forceinline__ unsigned short bfbits(float f) {
    __hip_bfloat16 h = __float2bfloat16(f);
    return *(unsigned short*)&h;
}

static __device__ __forceinline__ bf16x8 ld_frag(const ushort* p) {
    union { uint4 u; bf16x8 b; } cv;
    cv.u = *(const uint4*)p;
    return cv.b;
}

static __device__ __forceinline__ float fast_tanh(float x) {
    x = fminf(fmaxf(x, -15.f), 15.f);
    float e = __expf(2.f * x);
    return (e - 1.f) * __builtin_amdgcn_rcpf(e + 1.f);
}

// ---- repack: w -> wpk[tap][cout][ci] bf16 (taps 0-8); tap 9 = bias column ----
__global__ void repack_w(const float* __restrict__ w, const float* __restrict__ bias,
                         ushort* __restrict__ wpk) {
    int i = blockIdx.x * 256 + threadIdx.x;
    if (i < 9 * COUT * CIN) {
        int ci   = i & 15;
        int cout = (i >> 4) & 63;
        int tap  = i >> 10;
        wpk[i] = bfbits(w[(cout * CIN + ci) * 9 + tap]);
    } else if (i < 10 * COUT * CIN) {
        int j    = i - 9 * COUT * CIN;
        int ci   = j & 15;
        int cout = j >> 4;
        wpk[i] = (ci == 0) ? bfbits(bias[cout]) : (ushort)0;
    }
}

// Cout-split 8-wave blocks: wave (pgrp,mhalf) computes 32 couts x 64 px.
// Per-wave VGPR ~110 (wf 40 + acc 32 + fx 16 + addr) -> 4 waves/SIMD resident
// WITHOUT forcing (round-10 lesson: forced caps spill; round-9: latency-bound
// at ~2 blocks/CU). Wave pairs min-combine via 4KB LDS after the tile barrier.
__global__ __launch_bounds__(THREADS, 2)
void conv_min_tanh_cs(const float* __restrict__ x,
                      const ushort* __restrict__ wpk,
                      float* __restrict__ out) {
    __shared__ __align__(16) ushort xsm[2][TIN * TIN * CELL];  // 2 x 15552 B
    __shared__ float omin[2][4][2][64];                        // 4 KB

    // bijective XCD swizzle (2048 % 8 == 0)
    const int bid = blockIdx.x;                 // 0..2047
    const int L   = (bid & 7) * 256 + (bid >> 3);
    const int b   = L >> 5;
    const int rr  = L & 31;
    const int yb0 = (rr >> 4) * (NTY * TS);     // 0 or 128
    const int x0  = (rr & 15) * TS;

    const int tid   = threadIdx.x;
    const int lane  = tid & 63;
    const int wv    = tid >> 6;     // 0..7
    const int l31   = lane & 31;
    const int hi    = lane >> 5;    // k half: ci 0-7 vs 8-15
    const int pgrp  = wv >> 1;      // row group: rows pgrp*4 .. pgrp*4+3
    const int mhalf = wv & 1;       // cout half: mhalf*32 .. +31

    // ---- weights: 10 frags (9 taps + bias tap) for THIS cout half ----
    bf16x8 wf[10];
    #pragma unroll
    for (int tap = 0; tap < 10; ++tap)
        wf[tap] = ld_frag(wpk + tap * 1024 + (mhalf * 32 + l31) * 16 + hi * 8);

    // ones B-frag for the bias tap (k=0 lives in hi==0, elem 0)
    bf16x8 pone;
    #pragma unroll
    for (int j = 0; j < 8; ++j) pone[j] = 0;
    if (hi == 0) pone[0] = (short)0x3F80;

    // ---- staging precompute: one quad-item per thread (tid < 360) ----
    // item: cg (4 ci-planes), dy, q; quad covers cells dx0..dx0+3 (q=4: 16,17)
    const bool sval = tid < NQUAD;
    const int  it   = sval ? tid : 0;
    const int  cg   = it / 90;
    const int  r90  = it - cg * 90;
    const int  dy   = r90 / 5;
    const int  q    = r90 - dy * 5;
    const int  dx0  = (q < 4) ? q * 4 : 16;
    const int  gx0  = min(x0 + dx0, W - 4);   // clamp keeps float4 in-row;
                                              // mis-content only hits discard-only
                                              // halo cells (x0=240 audit)
    const int  ncell = (q == 4) ? 2 : 4;
    int lo[4];
    #pragma unroll
    for (int j = 0; j < 4; ++j)
        lo[j] = ((dy * TIN + dx0 + ((dx0 + j < TIN) ? j : 0)) * CELL + cg * 4);

    const float* pp0 = x + (size_t)b * (CIN * HW) + (size_t)(cg * 4) * HW;
    const float* pp1 = pp0 + HW;
    const float* pp2 = pp0 + 2 * HW;
    const float* pp3 = pp0 + 3 * HW;

    float4 f0, f1, f2, f3;

    auto stage_load = [&](int ybase) {
        if (sval) {
            int gy  = min(ybase + dy, H - 1);
            int idx = (gy << 8) + gx0;
            f0 = *(const float4*)&pp0[idx];
            f1 = *(const float4*)&pp1[idx];
            f2 = *(const float4*)&pp2[idx];
            f3 = *(const float4*)&pp3[idx];
        }
    };
    auto stage_write = [&](int buf) {
        if (sval) {
            const float e0[4] = {f0.x, f0.y, f0.z, f0.w};
            const float e1[4] = {f1.x, f1.y, f1.z, f1.w};
            const float e2[4] = {f2.x, f2.y, f2.z, f2.w};
            const float e3[4] = {f3.x, f3.y, f3.z, f3.w};
            #pragma unroll
            for (int j = 0; j < 4; ++j) {
                if (j < ncell) {
                    ushort4 v;
                    v.x = bfbits(e0[j]);
                    v.y = bfbits(e1[j]);
                    v.z = bfbits(e2[j]);
                    v.w = bfbits(e3[j]);
                    *(ushort4*)&xsm[buf][lo[j]] = v;
                }
            }
        }
    };

    // B-frag (pixel) cell bases: Ntile n -> row = pgrp*4 + n*2 + (l31>>4), col = l31&15
    const int row0 = pgrp * 4 + (l31 >> 4);
    const int cb0  = ((row0 * TIN) + (l31 & 15)) * CELL + hi * 8;
    const int cb1  = cb0 + 2 * TIN * CELL;

    // ---- prologue: stage tile 0 ----
    stage_load(yb0);
    stage_write(0);
    __syncthreads();

    #pragma unroll 1
    for (int t = 0; t < NTY; ++t) {
        const int cur = t & 1;

        // issue next tile's global loads before compute (latency rides out MFMAs)
        if (t + 1 < NTY) stage_load(yb0 + (t + 1) * TS);

        f32x16 acc0, acc1;
        #pragma unroll
        for (int r = 0; r < 16; ++r) { acc0[r] = 0.f; acc1[r] = 0.f; }

        const ushort* xt = &xsm[cur][0];
        #pragma unroll
        for (int tap = 0; tap < 9; ++tap) {
            const int kh = tap / 3, kw = tap - 3 * kh;
            const int toff = (kh * TIN + kw) * CELL;
            bf16x8 p0 = ld_frag(xt + cb0 + toff);
            bf16x8 p1 = ld_frag(xt + cb1 + toff);
            acc0 = __builtin_amdgcn_mfma_f32_32x32x16_bf16(wf[tap], p0, acc0, 0, 0, 0);
            acc1 = __builtin_amdgcn_mfma_f32_32x32x16_bf16(wf[tap], p1, acc1, 0, 0, 0);
        }
        // bias tap: D[cout][px] += bias[cout] * 1
        acc0 = __builtin_amdgcn_mfma_f32_32x32x16_bf16(wf[9], pone, acc0, 0, 0, 0);
        acc1 = __builtin_amdgcn_mfma_f32_32x32x16_bf16(wf[9], pone, acc1, 0, 0, 0);

        // ---- per-wave epilogue: min over this wave's 32 couts ----
        #pragma unroll
        for (int n = 0; n < 2; ++n) {
            f32x16& a = n ? acc1 : acc0;
            float v[16];
            #pragma unroll
            for (int r = 0; r < 16; ++r) v[r] = a[r];
            #pragma unroll
            for (int s = 8; s >= 1; s >>= 1)
                #pragma unroll
                for (int r = 0; r < s; ++r)
                    v[r] = fminf(v[r], v[r + s]);               // 16 couts in-reg
            float res = fminf(v[0], __shfl_xor(v[0], 32, 64));  // + 16 in lane^32
            if (hi == 0) omin[cur][pgrp][mhalf][n * 32 + l31] = res;
        }

        // write next tile into the other LDS buffer
        if (t + 1 < NTY) stage_write(cur ^ 1);
        __syncthreads();

        // ---- cross-wave combine + store for tile t (omin[cur] complete) ----
        if (tid < 256) {
            int pg = tid >> 6, j = tid & 63;
            float val = fminf(omin[cur][pg][0][j], omin[cur][pg][1][j]);
            int oy = yb0 + t * TS + pg * 4 + ((j >> 5) << 1) + ((j & 31) >> 4);
            int ox = x0 + (j & 15);
            if (oy < HO && ox < WO)
                out[((size_t)b * HO + oy) * WO + ox] = fast_tanh(fast_tanh(val));
        }
    }
}

extern "C" void kernel_launch(void* const* d_in, const int* in_sizes, int n_in,
                              void* d_out, int out_size, void* d_ws, size_t ws_size,
                              hipStream_t stream) {
    const float* x    = (const float*)d_in[0];
    const float* w    = (const float*)d_in[1];
    const float* bias = (const float*)d_in[2];
    float* out        = (float*)d_out;
    ushort* wpk       = (ushort*)d_ws;   // 10*64*16 bf16 = 20480 B

    hipLaunchKernelGGL(repack_w, dim3(40), dim3(256), 0, stream, w, bias, wpk);
    hipLaunchKernelGGL(conv_min_tanh_cs, dim3(2048), dim3(THREADS), 0, stream,
                       x, wpk, out);
}

// Round 12
// 113.664 us; speedup vs baseline: 4.8989x; 1.1885x over previous
//
#include <hip/hip_runtime.h>
#include <hip/hip_bf16.h>

#define BATCH 64
#define CIN   16
#define H     256
#define W     256
#define HW    (H*W)
#define COUT  64
#define HO    254
#define WO    254

#define TS      16            // output tile edge
#define TIN     18            // staged input tile edge
#define CELL    24            // ushorts per (y,x) cell: 16 ci + 8 pad (48B, 16B-aligned)
#define NTY     8             // y-tiles per block (half strip)
#define THREADS 512           // 8 waves
#define NQUAD   360           // staging quad-items per tile: 4 cg x 18 dy x 5 q

typedef short  bf16x8 __attribute__((ext_vector_type(8)));
typedef float  f32x16 __attribute__((ext_vector_type(16)));

static __device__ __forceinline__ unsigned short bfbits(float f) {
    __hip_bfloat16 h = __float2bfloat16(f);
    return *(unsigned short*)&h;
}

static __device__ __forceinline__ bf16x8 ld_frag(const ushort* p) {
    union { uint4 u; bf16x8 b; } cv;
    cv.u = *(const uint4*)p;
    return cv.b;
}

static __device__ __forceinline__ float fast_tanh(float x) {
    x = fminf(fmaxf(x, -15.f), 15.f);
    float e = __expf(2.f * x);
    return (e - 1.f) * __builtin_amdgcn_rcpf(e + 1.f);
}

// ---- repack: w -> wpk[tap][cout][ci] bf16 (taps 0-8); tap 9 = bias column ----
__global__ void repack_w(const float* __restrict__ w, const float* __restrict__ bias,
                         ushort* __restrict__ wpk) {
    int i = blockIdx.x * 256 + threadIdx.x;
    if (i < 9 * COUT * CIN) {
        int ci   = i & 15;
        int cout = (i >> 4) & 63;
        int tap  = i >> 10;
        wpk[i] = bfbits(w[(cout * CIN + ci) * 9 + tap]);
    } else if (i < 10 * COUT * CIN) {
        int j    = i - 9 * COUT * CIN;
        int ci   = j & 15;
        int cout = j >> 4;
        wpk[i] = (ci == 0) ? bfbits(bias[cout]) : (ushort)0;
    }
}

// Occupancy-forced round. Cross-round evidence: unforced configs pin at ~20%
// occupancy regardless of VGPR (72/124/128); amdgpu_waves_per_eu(6,8) hit 65%
// occ + 3.3 TB/s but spilled (budget 85 < demand 110). This kernel's true
// demand is 72 VGPR (R11 measured, no spill) -> waves_per_eu(4,8) budget=128
// is spill-safe while forcing ~4-6 waves/SIMD.
__global__ __launch_bounds__(THREADS) __attribute__((amdgpu_waves_per_eu(4, 8)))
void conv_min_tanh_cs(const float* __restrict__ x,
                      const ushort* __restrict__ wpk,
                      float* __restrict__ out) {
    __shared__ __align__(16) ushort xsm[2][TIN * TIN * CELL];  // 2 x 15552 B
    __shared__ float omin[2][4][2][64];                        // 4 KB

    // bijective XCD swizzle (2048 % 8 == 0)
    const int bid = blockIdx.x;                 // 0..2047
    const int L   = (bid & 7) * 256 + (bid >> 3);
    const int b   = L >> 5;
    const int rr  = L & 31;
    const int yb0 = (rr >> 4) * (NTY * TS);     // 0 or 128
    const int x0  = (rr & 15) * TS;

    const int tid   = threadIdx.x;
    const int lane  = tid & 63;
    const int wv    = tid >> 6;     // 0..7
    const int l31   = lane & 31;
    const int hi    = lane >> 5;    // k half: ci 0-7 vs 8-15
    const int pgrp  = wv >> 1;      // row group: rows pgrp*4 .. pgrp*4+3
    const int mhalf = wv & 1;       // cout half: mhalf*32 .. +31

    // ---- weights: 10 frags (9 taps + bias tap) for THIS cout half ----
    bf16x8 wf[10];
    #pragma unroll
    for (int tap = 0; tap < 10; ++tap)
        wf[tap] = ld_frag(wpk + tap * 1024 + (mhalf * 32 + l31) * 16 + hi * 8);

    // ones B-frag for the bias tap (k=0 lives in hi==0, elem 0)
    bf16x8 pone;
    #pragma unroll
    for (int j = 0; j < 8; ++j) pone[j] = 0;
    if (hi == 0) pone[0] = (short)0x3F80;

    // ---- staging precompute: one quad-item per thread (tid < 360) ----
    const bool sval = tid < NQUAD;
    const int  it   = sval ? tid : 0;
    const int  cg   = it / 90;
    const int  r90  = it - cg * 90;
    const int  dy   = r90 / 5;
    const int  q    = r90 - dy * 5;
    const int  dx0  = (q < 4) ? q * 4 : 16;
    const int  gx0  = min(x0 + dx0, W - 4);   // clamp keeps float4 in-row;
                                              // mis-content only hits discard-only
                                              // halo cells (x0=240 audit)
    const int  ncell = (q == 4) ? 2 : 4;
    int lo[4];
    #pragma unroll
    for (int j = 0; j < 4; ++j)
        lo[j] = ((dy * TIN + dx0 + ((dx0 + j < TIN) ? j : 0)) * CELL + cg * 4);

    const float* pp0 = x + (size_t)b * (CIN * HW) + (size_t)(cg * 4) * HW;
    const float* pp1 = pp0 + HW;
    const float* pp2 = pp0 + 2 * HW;
    const float* pp3 = pp0 + 3 * HW;

    float4 f0, f1, f2, f3;

    auto stage_load = [&](int ybase) {
        if (sval) {
            int gy  = min(ybase + dy, H - 1);
            int idx = (gy << 8) + gx0;
            f0 = *(const float4*)&pp0[idx];
            f1 = *(const float4*)&pp1[idx];
            f2 = *(const float4*)&pp2[idx];
            f3 = *(const float4*)&pp3[idx];
        }
    };
    auto stage_write = [&](int buf) {
        if (sval) {
            const float e0[4] = {f0.x, f0.y, f0.z, f0.w};
            const float e1[4] = {f1.x, f1.y, f1.z, f1.w};
            const float e2[4] = {f2.x, f2.y, f2.z, f2.w};
            const float e3[4] = {f3.x, f3.y, f3.z, f3.w};
            #pragma unroll
            for (int j = 0; j < 4; ++j) {
                if (j < ncell) {
                    ushort4 v;
                    v.x = bfbits(e0[j]);
                    v.y = bfbits(e1[j]);
                    v.z = bfbits(e2[j]);
                    v.w = bfbits(e3[j]);
                    *(ushort4*)&xsm[buf][lo[j]] = v;
                }
            }
        }
    };

    // B-frag cell bases: Ntile n -> row = pgrp*4 + n*2 + (l31>>4), col = l31&15
    const int row0 = pgrp * 4 + (l31 >> 4);
    const int cb0  = ((row0 * TIN) + (l31 & 15)) * CELL + hi * 8;
    const int cb1  = cb0 + 2 * TIN * CELL;

    // ---- prologue: stage tile 0 ----
    stage_load(yb0);
    stage_write(0);
    __syncthreads();

    #pragma unroll 1
    for (int t = 0; t < NTY; ++t) {
        const int cur = t & 1;

        // issue next tile's global loads before compute
        if (t + 1 < NTY) stage_load(yb0 + (t + 1) * TS);

        f32x16 acc0, acc1;
        #pragma unroll
        for (int r = 0; r < 16; ++r) { acc0[r] = 0.f; acc1[r] = 0.f; }

        const ushort* xt = &xsm[cur][0];
        #pragma unroll
        for (int tap = 0; tap < 9; ++tap) {
            const int kh = tap / 3, kw = tap - 3 * kh;
            const int toff = (kh * TIN + kw) * CELL;
            bf16x8 p0 = ld_frag(xt + cb0 + toff);
            bf16x8 p1 = ld_frag(xt + cb1 + toff);
            acc0 = __builtin_amdgcn_mfma_f32_32x32x16_bf16(wf[tap], p0, acc0, 0, 0, 0);
            acc1 = __builtin_amdgcn_mfma_f32_32x32x16_bf16(wf[tap], p1, acc1, 0, 0, 0);
        }
        // bias tap
        acc0 = __builtin_amdgcn_mfma_f32_32x32x16_bf16(wf[9], pone, acc0, 0, 0, 0);
        acc1 = __builtin_amdgcn_mfma_f32_32x32x16_bf16(wf[9], pone, acc1, 0, 0, 0);

        // ---- per-wave epilogue: min over this wave's 32 couts ----
        #pragma unroll
        for (int n = 0; n < 2; ++n) {
            f32x16& a = n ? acc1 : acc0;
            float v[16];
            #pragma unroll
            for (int r = 0; r < 16; ++r) v[r] = a[r];
            #pragma unroll
            for (int s = 8; s >= 1; s >>= 1)
                #pragma unroll
                for (int r = 0; r < s; ++r)
                    v[r] = fminf(v[r], v[r + s]);               // 16 couts in-reg
            float res = fminf(v[0], __shfl_xor(v[0], 32, 64));  // + 16 in lane^32
            if (hi == 0) omin[cur][pgrp][mhalf][n * 32 + l31] = res;
        }

        // write next tile into the other LDS buffer
        if (t + 1 < NTY) stage_write(cur ^ 1);
        __syncthreads();

        // ---- cross-wave combine + store (balanced: every wave, own 64 px) ----
        if (mhalf == 0) {
            float val = fminf(omin[cur][pgrp][0][lane], omin[cur][pgrp][1][lane]);
            int oy = yb0 + t * TS + pgrp * 4 + ((lane >> 5) << 1) + ((lane & 31) >> 4);
            int ox = x0 + (lane & 15);
            if (oy < HO && ox < WO)
                out[((size_t)b * HO + oy) * WO + ox] = fast_tanh(fast_tanh(val));
        }
    }
}

extern "C" void kernel_launch(void* const* d_in, const int* in_sizes, int n_in,
                              void* d_out, int out_size, void* d_ws, size_t ws_size,
                              hipStream_t stream) {
    const float* x    = (const float*)d_in[0];
    const float* w    = (const float*)d_in[1];
    const float* bias = (const float*)d_in[2];
    float* out        = (float*)d_out;
    ushort* wpk       = (ushort*)d_ws;   // 10*64*16 bf16 = 20480 B

    hipLaunchKernelGGL(repack_w, dim3(40), dim3(256), 0, stream, w, bias, wpk);
    hipLaunchKernelGGL(conv_min_tanh_cs, dim3(2048), dim3(THREADS), 0, stream,
                       x, wpk, out);
}